// Round 3
// baseline (1457.926 us; speedup 1.0000x reference)
//
#include <hip/hip_runtime.h>
#include <hip/hip_bf16.h>
#include <math.h>

typedef __hip_bfloat16 bf16;

// Problem constants (EfficientViT block): B=64, DIM=256, HID=512, NH=4, KD=16, D=64, 28x28, WH=7
#define BB    64
#define DIMC  256
#define HIDC  512
#define NHH   4
#define KDC   16
#define DHC   64
#define HH_   28
#define WW_   28
#define PP    784   // 28*28

__device__ __forceinline__ float toF(float x) { return x; }
__device__ __forceinline__ float toF(bf16 x) { return __bfloat162float(x); }
__device__ __forceinline__ void stV(float* p, float v) { *p = v; }
__device__ __forceinline__ void stV(bf16* p, float v) { *p = __float2bfloat16(v); }

// ---------------------------------------------------------------------------
// Depthwise 3x3 conv + BN + residual-add of the input:  out = in + s*conv(in) + b
// One block per (n,c) plane.
// ---------------------------------------------------------------------------
__global__ __launch_bounds__(256) void dw3x3_kernel(
    const float* __restrict__ in, const float* __restrict__ w,
    const float* __restrict__ s, const float* __restrict__ b,
    float* __restrict__ out)
{
    int nc = blockIdx.x;          // n*256 + c
    int c  = nc & (DIMC - 1);
    const float* ip = in + (size_t)nc * PP;
    float*       op = out + (size_t)nc * PP;
    float w9[9];
#pragma unroll
    for (int i = 0; i < 9; i++) w9[i] = w[c * 9 + i];
    float sc = s[c], bb = b[c];
    for (int p = threadIdx.x; p < PP; p += 256) {
        int h = p / WW_, x = p % WW_;
        float acc = 0.f;
#pragma unroll
        for (int i = 0; i < 3; i++) {
            int hh = h + i - 1;
            if (hh < 0 || hh >= HH_) continue;
#pragma unroll
            for (int j = 0; j < 3; j++) {
                int xx = x + j - 1;
                if (xx < 0 || xx >= WW_) continue;
                acc += w9[i * 3 + j] * ip[hh * WW_ + xx];
            }
        }
        op[p] = ip[p] + acc * sc + bb;
    }
}

// ---------------------------------------------------------------------------
// Per-head depthwise 5x5 conv + BN on the q part of qkv.
// qkv layout: [B][384][784] fp32, q channel of head hh, kc  ->  hh*96+kc.
// Output: Q [B][64][784] fp32 (channel = hh*16+kc).  No residual.
// ---------------------------------------------------------------------------
__global__ __launch_bounds__(256) void dws5x5_kernel(
    const float* __restrict__ qkv, const float* __restrict__ w,
    const float* __restrict__ s, const float* __restrict__ b,
    float* __restrict__ qout)
{
    int blk = blockIdx.x;         // n*64 + hh*16 + kc
    int n = blk >> 6, hk = blk & 63;
    int hh = hk >> 4, kc = hk & 15;
    const float* ip = qkv + ((size_t)n * 384 + hh * 96 + kc) * PP;
    float*       op = qout + (size_t)blk * PP;
    float w25[25];
#pragma unroll
    for (int i = 0; i < 25; i++) w25[i] = w[hk * 25 + i];
    float sc = s[hk], bb = b[hk];
    for (int p = threadIdx.x; p < PP; p += 256) {
        int h = p / WW_, x = p % WW_;
        float acc = 0.f;
#pragma unroll
        for (int i = 0; i < 5; i++) {
            int h2 = h + i - 2;
            if (h2 < 0 || h2 >= HH_) continue;
#pragma unroll
            for (int j = 0; j < 5; j++) {
                int x2 = x + j - 2;
                if (x2 < 0 || x2 >= WW_) continue;
                acc += w25[i * 5 + j] * ip[h2 * WW_ + x2];
            }
        }
        op[p] = acc * sc + bb;
    }
}

// ---------------------------------------------------------------------------
// 1x1 conv = per-image GEMM  out[n,co,p] = sum_ci W[co,ci]*in[n,ci,p]
// BN (+optional ReLU) (+optional fp32 residual) epilogue; Tout = fp32 or bf16.
// 64x64 tile, 256 threads, 4x4 register tile per thread, float4 LDS reads.
// grid = (ceil(784/64)=13, Cout/64, B)
// ---------------------------------------------------------------------------
template <typename Tin, typename Tout, bool RELU, bool RES>
__global__ __launch_bounds__(256) void conv1x1_kernel(
    const Tin* __restrict__ in, const float* __restrict__ W,
    const float* __restrict__ S, const float* __restrict__ Bb,
    const float* __restrict__ res, Tout* __restrict__ out,
    int Cin, int Cout)
{
    int n   = blockIdx.z;
    int co0 = blockIdx.y * 64;
    int p0  = blockIdx.x * 64;
    int tid = threadIdx.x;
    int tx = tid & 15, ty = tid >> 4;

    __shared__ __align__(16) float A_lds[16][68];  // [kk][co]  (68*4=272B rows keep float4 alignment)
    __shared__ __align__(16) float B_lds[16][64];  // [kk][p]

    float acc[4][4] = {};

    for (int k0 = 0; k0 < Cin; k0 += 16) {
        // A: W[co0+r][k0+kk], transposed into A_lds[kk][r]
        {
            int r   = tid >> 2;          // 0..63
            int kk0 = (tid & 3) * 4;     // 0,4,8,12
            const float* wp = W + (size_t)(co0 + r) * Cin + k0 + kk0;
#pragma unroll
            for (int e = 0; e < 4; e++) A_lds[kk0 + e][r] = wp[e];
        }
        // B: in[n][k0+kk][p0+pp]
#pragma unroll
        for (int e = 0; e < 4; e++) {
            int idx = tid + e * 256;
            int kk = idx >> 6, pp = idx & 63;
            int p = p0 + pp;
            float v = 0.f;
            if (p < PP) v = toF(in[((size_t)n * Cin + k0 + kk) * PP + p]);
            B_lds[kk][pp] = v;
        }
        __syncthreads();
#pragma unroll
        for (int kk = 0; kk < 16; kk++) {
            float4 av = *(const float4*)&A_lds[kk][ty * 4];
            float4 bv = *(const float4*)&B_lds[kk][tx * 4];
            float a[4] = {av.x, av.y, av.z, av.w};
            float b[4] = {bv.x, bv.y, bv.z, bv.w};
#pragma unroll
            for (int i = 0; i < 4; i++)
#pragma unroll
                for (int j = 0; j < 4; j++) acc[i][j] += a[i] * b[j];
        }
        __syncthreads();
    }

    int p = p0 + tx * 4;
    if (p < PP) {   // PP % 4 == 0, so p..p+3 all in-bounds when p < PP
#pragma unroll
        for (int i = 0; i < 4; i++) {
            int co = co0 + ty * 4 + i;
            float sc = S[co], bb = Bb[co];
            size_t base = ((size_t)n * Cout + co) * PP + p;
#pragma unroll
            for (int j = 0; j < 4; j++) {
                float y = acc[i][j] * sc + bb;
                if (RELU) y = fmaxf(y, 0.f);
                if (RES) y += res[base + j];
                stV(&out[base + j], y);
            }
        }
    }
}

// ---------------------------------------------------------------------------
// Local 7x7 window attention.  One block per (n, head, wi, wj).
// Q: fp32 [B][64][784] (post-dws).  K,V from fp32 qkv buffer.
// Writes O = relu(attn@V) as fp32 [B][256][784] (channel = hh*64+d).
// ---------------------------------------------------------------------------
__global__ __launch_bounds__(256) void attn_kernel(
    const float* __restrict__ Q, const float* __restrict__ Hq,
    const float* __restrict__ pos, float* __restrict__ O)
{
    int blk = blockIdx.x;  // ((n*4+hh)*4+wi)*4+wj
    int wj = blk & 3, wi = (blk >> 2) & 3, hh = (blk >> 4) & 3, n = blk >> 6;
    int h0 = wi * 7, w0 = wj * 7;
    int tid = threadIdx.x;

    __shared__ float q_lds[16][49];
    __shared__ float k_lds[16][49];
    __shared__ float v_lds[49][64];
    __shared__ float s_lds[49][52];

    for (int idx = tid; idx < 16 * 49; idx += 256) {
        int kc = idx / 49, qi = idx % 49;
        int h = h0 + qi / 7, w = w0 + qi % 7;
        q_lds[kc][qi] = Q[((size_t)n * 64 + hh * 16 + kc) * PP + h * WW_ + w];
        k_lds[kc][qi] = Hq[((size_t)n * 384 + hh * 96 + 16 + kc) * PP + h * WW_ + w];
    }
    for (int idx = tid; idx < 49 * 64; idx += 256) {
        int d = idx / 49, ki = idx % 49;
        int h = h0 + ki / 7, w = w0 + ki % 7;
        v_lds[ki][d] = Hq[((size_t)n * 384 + hh * 96 + 32 + d) * PP + h * WW_ + w];
    }
    __syncthreads();

    const float scale = 0.25f;  // KD^-0.5
    for (int idx = tid; idx < 49 * 49; idx += 256) {
        int qi = idx / 49, ki = idx % 49;
        float acc = 0.f;
#pragma unroll
        for (int kc = 0; kc < 16; kc++) acc += q_lds[kc][qi] * k_lds[kc][ki];
        s_lds[qi][ki] = acc * scale + pos[(hh * 49 + qi) * 49 + ki];
    }
    __syncthreads();

    if (tid < 49) {
        float m = -1e30f;
        for (int ki = 0; ki < 49; ki++) m = fmaxf(m, s_lds[tid][ki]);
        float sum = 0.f;
        for (int ki = 0; ki < 49; ki++) {
            float e = __expf(s_lds[tid][ki] - m);
            s_lds[tid][ki] = e;
            sum += e;
        }
        float inv = 1.f / sum;
        for (int ki = 0; ki < 49; ki++) s_lds[tid][ki] *= inv;
    }
    __syncthreads();

    for (int idx = tid; idx < 49 * 64; idx += 256) {
        int qi = idx >> 6, d = idx & 63;
        float acc = 0.f;
        for (int ki = 0; ki < 49; ki++) acc += s_lds[qi][ki] * v_lds[ki][d];
        float y = fmaxf(acc, 0.f);
        int h = h0 + qi / 7, w = w0 + qi % 7;
        O[((size_t)n * 256 + hh * 64 + d) * PP + h * WW_ + w] = y;
    }
}

// ---------------------------------------------------------------------------
extern "C" void kernel_launch(void* const* d_in, const int* in_sizes, int n_in,
                              void* d_out, int out_size, void* d_ws, size_t ws_size,
                              hipStream_t stream)
{
    // setup_inputs() dict order — ALL inputs are float32 per the reference.
    const float* x0     = (const float*)d_in[0];
    const float* dw0_w  = (const float*)d_in[1];
    const float* dw0_s  = (const float*)d_in[2];
    const float* dw0_b  = (const float*)d_in[3];
    const float* dw1_w  = (const float*)d_in[4];
    const float* dw1_s  = (const float*)d_in[5];
    const float* dw1_b  = (const float*)d_in[6];
    const float* f0w1   = (const float*)d_in[7];
    const float* f0s1   = (const float*)d_in[8];
    const float* f0b1   = (const float*)d_in[9];
    const float* f0w2   = (const float*)d_in[10];
    const float* f0s2   = (const float*)d_in[11];
    const float* f0b2   = (const float*)d_in[12];
    const float* f1w1   = (const float*)d_in[13];
    const float* f1s1   = (const float*)d_in[14];
    const float* f1b1   = (const float*)d_in[15];
    const float* f1w2   = (const float*)d_in[16];
    const float* f1s2   = (const float*)d_in[17];
    const float* f1b2   = (const float*)d_in[18];
    const float* qkv_w  = (const float*)d_in[19];
    const float* qkv_s  = (const float*)d_in[20];
    const float* qkv_b  = (const float*)d_in[21];
    const float* dws_w  = (const float*)d_in[22];
    const float* dws_s  = (const float*)d_in[23];
    const float* dws_b  = (const float*)d_in[24];
    const float* proj_w = (const float*)d_in[25];
    const float* proj_s = (const float*)d_in[26];
    const float* proj_b = (const float*)d_in[27];
    const float* pos    = (const float*)d_in[28];

    // -------- workspace layout (aliased, ~172 MB total) --------
    // A: X1 fp32 [B][256][784]                       (live steps 1..3d)
    // B: Hb bf16 [B][512][784]  (steps 2a-2b, 5a-5b) | Qb fp32 [B][64][784] (step 3b-3c)
    // C: QKV fp32 [B][384][784] (steps 3a-3c)        | X2 fp32 [B][256][784] (steps 4-5)
    // O  fp32 [B][256][784] lives in d_out (step 3c-3d), overwritten by final output (5b).
    const size_t NXf = (size_t)BB * DIMC * PP;        // 12,845,056 floats = 51,380,224 B
    float* X1   = (float*)d_ws;
    char*  Bbase = (char*)d_ws + NXf * 4;
    bf16*  Hb   = (bf16*)Bbase;                       // 51,380,224 B
    float* Qb   = (float*)Bbase;                      // 12,845,056 B (aliases Hb, disjoint in time)
    char*  Cbase = Bbase + (size_t)BB * HIDC * PP * 2;
    float* QKV  = (float*)Cbase;                      // 77,070,336 B
    float* X2   = (float*)Cbase;                      // aliases QKV, disjoint in time
    float* Ob   = (float*)d_out;                      // scratch in d_out until final write
    float* outp = (float*)d_out;

    dim3 blk(256);

    // 1) x = x + dw0(x)
    dw3x3_kernel<<<BB * DIMC, blk, 0, stream>>>(x0, dw0_w, dw0_s, dw0_b, X1);

    // 2) ffn0
    conv1x1_kernel<float, bf16, true, false><<<dim3(13, HIDC / 64, BB), blk, 0, stream>>>(
        X1, f0w1, f0s1, f0b1, nullptr, Hb, DIMC, HIDC);
    conv1x1_kernel<bf16, float, false, true><<<dim3(13, DIMC / 64, BB), blk, 0, stream>>>(
        Hb, f0w2, f0s2, f0b2, X1, X1, HIDC, DIMC);

    // 3) attention
    conv1x1_kernel<float, float, false, false><<<dim3(13, 384 / 64, BB), blk, 0, stream>>>(
        X1, qkv_w, qkv_s, qkv_b, nullptr, QKV, DIMC, 384);
    dws5x5_kernel<<<BB * 64, blk, 0, stream>>>(QKV, dws_w, dws_s, dws_b, Qb);
    attn_kernel<<<BB * NHH * 16, blk, 0, stream>>>(Qb, QKV, pos, Ob);
    conv1x1_kernel<float, float, false, true><<<dim3(13, DIMC / 64, BB), blk, 0, stream>>>(
        Ob, proj_w, proj_s, proj_b, X1, X1, DIMC, DIMC);

    // 4) x = x + dw1(x)   (ping-pong into C; QKV dead)
    dw3x3_kernel<<<BB * DIMC, blk, 0, stream>>>(X1, dw1_w, dw1_s, dw1_b, X2);

    // 5) ffn1, final fp32 store to d_out
    conv1x1_kernel<float, bf16, true, false><<<dim3(13, HIDC / 64, BB), blk, 0, stream>>>(
        X2, f1w1, f1s1, f1b1, nullptr, Hb, DIMC, HIDC);
    conv1x1_kernel<bf16, float, false, true><<<dim3(13, DIMC / 64, BB), blk, 0, stream>>>(
        Hb, f1w2, f1s2, f1b2, X2, outp, HIDC, DIMC);
}

// Round 5
// 913.305 us; speedup vs baseline: 1.5963x; 1.5963x over previous
//
#include <hip/hip_runtime.h>
#include <hip/hip_bf16.h>
#include <math.h>

typedef __hip_bfloat16 bf16;
typedef __attribute__((ext_vector_type(8))) short short8;   // 8 x bf16 MFMA frag
typedef __attribute__((ext_vector_type(4))) float floatx4;  // 4 x f32 MFMA acc

// Problem constants (EfficientViT block): B=64, DIM=256, HID=512, NH=4, KD=16, D=64, 28x28, WH=7
#define BB    64
#define DIMC  256
#define HIDC  512
#define NHH   4
#define HH_   28
#define WW_   28
#define PP    784   // 28*28

__device__ __forceinline__ float toF(float x) { return x; }
__device__ __forceinline__ float toF(bf16 x) { return __bfloat162float(x); }
__device__ __forceinline__ void stV(float* p, float v) { *p = v; }
__device__ __forceinline__ void stV(bf16* p, float v) { *p = __float2bfloat16(v); }

// ---------------------------------------------------------------------------
// fp32 -> bf16 weight convert (linear copy)
// ---------------------------------------------------------------------------
__global__ __launch_bounds__(256) void cvt_f2b(
    const float* __restrict__ s, bf16* __restrict__ d, int n)
{
    int i = blockIdx.x * 256 + threadIdx.x;
    if (i < n) d[i] = __float2bfloat16(s[i]);
}

// ---------------------------------------------------------------------------
// Depthwise 3x3 conv + BN + residual (NCHW) — UNCHANGED from round 3 (proven)
// ---------------------------------------------------------------------------
__global__ __launch_bounds__(256) void dw3x3_kernel(
    const float* __restrict__ in, const float* __restrict__ w,
    const float* __restrict__ s, const float* __restrict__ b,
    float* __restrict__ out)
{
    int nc = blockIdx.x;          // n*256 + c
    int c  = nc & (DIMC - 1);
    const float* ip = in + (size_t)nc * PP;
    float*       op = out + (size_t)nc * PP;
    float w9[9];
#pragma unroll
    for (int i = 0; i < 9; i++) w9[i] = w[c * 9 + i];
    float sc = s[c], bb = b[c];
    for (int p = threadIdx.x; p < PP; p += 256) {
        int h = p / WW_, x = p % WW_;
        float acc = 0.f;
#pragma unroll
        for (int i = 0; i < 3; i++) {
            int hh = h + i - 1;
            if (hh < 0 || hh >= HH_) continue;
#pragma unroll
            for (int j = 0; j < 3; j++) {
                int xx = x + j - 1;
                if (xx < 0 || xx >= WW_) continue;
                acc += w9[i * 3 + j] * ip[hh * WW_ + xx];
            }
        }
        op[p] = ip[p] + acc * sc + bb;
    }
}

// ---------------------------------------------------------------------------
// Per-head depthwise 5x5 + BN on q (NCHW) — UNCHANGED from round 3 (proven)
// ---------------------------------------------------------------------------
__global__ __launch_bounds__(256) void dws5x5_kernel(
    const float* __restrict__ qkv, const float* __restrict__ w,
    const float* __restrict__ s, const float* __restrict__ b,
    float* __restrict__ qout)
{
    int blk = blockIdx.x;         // n*64 + hh*16 + kc
    int n = blk >> 6, hk = blk & 63;
    int hh = hk >> 4, kc = hk & 15;
    const float* ip = qkv + ((size_t)n * 384 + hh * 96 + kc) * PP;
    float*       op = qout + (size_t)blk * PP;
    float w25[25];
#pragma unroll
    for (int i = 0; i < 25; i++) w25[i] = w[hk * 25 + i];
    float sc = s[hk], bb = b[hk];
    for (int p = threadIdx.x; p < PP; p += 256) {
        int h = p / WW_, x = p % WW_;
        float acc = 0.f;
#pragma unroll
        for (int i = 0; i < 5; i++) {
            int h2 = h + i - 2;
            if (h2 < 0 || h2 >= HH_) continue;
#pragma unroll
            for (int j = 0; j < 5; j++) {
                int x2 = x + j - 2;
                if (x2 < 0 || x2 >= WW_) continue;
                acc += w25[i * 5 + j] * ip[h2 * WW_ + x2];
            }
        }
        op[p] = acc * sc + bb;
    }
}

// ---------------------------------------------------------------------------
// 1x1 conv as bf16 MFMA GEMM (NCHW):  out[n,co,p] = sum_ci W[co,ci] * X[n,ci,p]
// THE ONLY CHANGED PIECE vs round 3.
// Block 256 = 4 waves; tile 64(co) x 64(p); K-step 32.
//  - B staged to LDS [p][k] pitch 40 (on-the-fly NCHW transpose + bf16 cvt),
//    fragment = one aligned ds_read_b128.
//  - A fragment straight from global bf16 weights (L2-hot): one 16B load.
// Fragment layouts (HW-verified m89/m120):
//  A[m=lane&15][k=quad*8+j]  B[k=quad*8+j][n=lane&15]  D[row=quad*4+r][col=lane&15]
// grid (13, M/64, 64)
// ---------------------------------------------------------------------------
template <typename Tin, typename Tout, bool RELU, bool RES>
__global__ __launch_bounds__(256) void gemm_mfma(
    const bf16* __restrict__ Wb,    // [M][K] bf16
    const Tin*  __restrict__ X,     // [64][K][784]
    const float* __restrict__ S, const float* __restrict__ Bb,
    const float* __restrict__ res,  // [64][M][784] fp32 (if RES)
    Tout* __restrict__ out,         // [64][M][784]
    int M, int K)
{
    int n    = blockIdx.z;
    int co0  = blockIdx.y * 64;
    int p0   = blockIdx.x * 64;
    int tid  = threadIdx.x;
    int wv   = tid >> 6;      // wave 0..3 -> co sub-tile of 16
    int ln   = tid & 63;
    int l15  = ln & 15;
    int quad = ln >> 4;

    __shared__ __align__(16) bf16 Blds[64 * 40];   // [pp][kk], pitch 40 (80B rows, 16B-aligned)

    floatx4 acc[4];
#pragma unroll
    for (int t = 0; t < 4; t++) acc[t] = (floatx4){0.f, 0.f, 0.f, 0.f};

    const bf16* Arow = Wb + (size_t)(co0 + wv * 16 + l15) * K + quad * 8;
    const Tin*  Xn   = X + (size_t)n * K * PP;

    for (int k0 = 0; k0 < K; k0 += 32) {
        // stage B-tile: 32 k-rows x 64 p, coalesced global reads, transpose into LDS
#pragma unroll
        for (int e = 0; e < 8; e++) {
            int idx = tid + e * 256;
            int kk = idx >> 6, pp = idx & 63;
            int p = p0 + pp;
            float v = (p < PP) ? toF(Xn[(size_t)(k0 + kk) * PP + p]) : 0.f;
            Blds[pp * 40 + kk] = __float2bfloat16(v);
        }
        short8 afrag = *(const short8*)(Arow + k0);
        __syncthreads();
#pragma unroll
        for (int t = 0; t < 4; t++) {
            short8 bfrag = *(const short8*)&Blds[(t * 16 + l15) * 40 + quad * 8];
            acc[t] = __builtin_amdgcn_mfma_f32_16x16x32_bf16(afrag, bfrag, acc[t], 0, 0, 0);
        }
        __syncthreads();
    }

    // epilogue: lane holds C[co = co0+wv*16+quad*4+r][p = p0+t*16+l15]
    int cobase = co0 + wv * 16 + quad * 4;
    float s4[4], b4[4];
#pragma unroll
    for (int r = 0; r < 4; r++) { s4[r] = S[cobase + r]; b4[r] = Bb[cobase + r]; }

#pragma unroll
    for (int t = 0; t < 4; t++) {
        int p = p0 + t * 16 + l15;
        if (p >= PP) continue;
#pragma unroll
        for (int r = 0; r < 4; r++) {
            float y = acc[t][r] * s4[r] + b4[r];
            if (RELU) y = fmaxf(y, 0.f);
            size_t o = ((size_t)n * M + cobase + r) * PP + p;
            if (RES) y += res[o];
            stV(&out[o], y);
        }
    }
}

// ---------------------------------------------------------------------------
// 7x7 window attention (NCHW) — UNCHANGED from round 3 (proven)
// ---------------------------------------------------------------------------
__global__ __launch_bounds__(256) void attn_kernel(
    const float* __restrict__ Q, const float* __restrict__ Hq,
    const float* __restrict__ pos, float* __restrict__ O)
{
    int blk = blockIdx.x;  // ((n*4+hh)*4+wi)*4+wj
    int wj = blk & 3, wi = (blk >> 2) & 3, hh = (blk >> 4) & 3, n = blk >> 6;
    int h0 = wi * 7, w0 = wj * 7;
    int tid = threadIdx.x;

    __shared__ float q_lds[16][49];
    __shared__ float k_lds[16][49];
    __shared__ float v_lds[49][64];
    __shared__ float s_lds[49][52];

    for (int idx = tid; idx < 16 * 49; idx += 256) {
        int kc = idx / 49, qi = idx % 49;
        int h = h0 + qi / 7, w = w0 + qi % 7;
        q_lds[kc][qi] = Q[((size_t)n * 64 + hh * 16 + kc) * PP + h * WW_ + w];
        k_lds[kc][qi] = Hq[((size_t)n * 384 + hh * 96 + 16 + kc) * PP + h * WW_ + w];
    }
    for (int idx = tid; idx < 49 * 64; idx += 256) {
        int d = idx / 49, ki = idx % 49;
        int h = h0 + ki / 7, w = w0 + ki % 7;
        v_lds[ki][d] = Hq[((size_t)n * 384 + hh * 96 + 32 + d) * PP + h * WW_ + w];
    }
    __syncthreads();

    const float scale = 0.25f;  // KD^-0.5
    for (int idx = tid; idx < 49 * 49; idx += 256) {
        int qi = idx / 49, ki = idx % 49;
        float acc = 0.f;
#pragma unroll
        for (int kc = 0; kc < 16; kc++) acc += q_lds[kc][qi] * k_lds[kc][ki];
        s_lds[qi][ki] = acc * scale + pos[(hh * 49 + qi) * 49 + ki];
    }
    __syncthreads();

    if (tid < 49) {
        float m = -1e30f;
        for (int ki = 0; ki < 49; ki++) m = fmaxf(m, s_lds[tid][ki]);
        float sum = 0.f;
        for (int ki = 0; ki < 49; ki++) {
            float e = __expf(s_lds[tid][ki] - m);
            s_lds[tid][ki] = e;
            sum += e;
        }
        float inv = 1.f / sum;
        for (int ki = 0; ki < 49; ki++) s_lds[tid][ki] *= inv;
    }
    __syncthreads();

    for (int idx = tid; idx < 49 * 64; idx += 256) {
        int qi = idx >> 6, d = idx & 63;
        float acc = 0.f;
        for (int ki = 0; ki < 49; ki++) acc += s_lds[qi][ki] * v_lds[ki][d];
        float y = fmaxf(acc, 0.f);
        int h = h0 + qi / 7, w = w0 + qi % 7;
        O[((size_t)n * 256 + hh * 64 + d) * PP + h * WW_ + w] = y;
    }
}

// ---------------------------------------------------------------------------
extern "C" void kernel_launch(void* const* d_in, const int* in_sizes, int n_in,
                              void* d_out, int out_size, void* d_ws, size_t ws_size,
                              hipStream_t stream)
{
    // setup_inputs() dict order — all inputs float32.
    const float* x0     = (const float*)d_in[0];
    const float* dw0_w  = (const float*)d_in[1];
    const float* dw0_s  = (const float*)d_in[2];
    const float* dw0_b  = (const float*)d_in[3];
    const float* dw1_w  = (const float*)d_in[4];
    const float* dw1_s  = (const float*)d_in[5];
    const float* dw1_b  = (const float*)d_in[6];
    const float* f0w1   = (const float*)d_in[7];
    const float* f0s1   = (const float*)d_in[8];
    const float* f0b1   = (const float*)d_in[9];
    const float* f0w2   = (const float*)d_in[10];
    const float* f0s2   = (const float*)d_in[11];
    const float* f0b2   = (const float*)d_in[12];
    const float* f1w1   = (const float*)d_in[13];
    const float* f1s1   = (const float*)d_in[14];
    const float* f1b1   = (const float*)d_in[15];
    const float* f1w2   = (const float*)d_in[16];
    const float* f1s2   = (const float*)d_in[17];
    const float* f1b2   = (const float*)d_in[18];
    const float* qkv_w  = (const float*)d_in[19];
    const float* qkv_s  = (const float*)d_in[20];
    const float* qkv_b  = (const float*)d_in[21];
    const float* dws_w  = (const float*)d_in[22];
    const float* dws_s  = (const float*)d_in[23];
    const float* dws_b  = (const float*)d_in[24];
    const float* proj_w = (const float*)d_in[25];
    const float* proj_s = (const float*)d_in[26];
    const float* proj_b = (const float*)d_in[27];
    const float* pos    = (const float*)d_in[28];

    // -------- workspace layout: ROUND-3 PROVEN + bf16 weights appended ------
    // A: X1 fp32 [B][256][784]
    // B: Hb bf16 [B][512][784] | Qb fp32 [B][64][784] (disjoint in time)
    // C: QKV fp32 [B][384][784] | X2 fp32 [B][256][784] (disjoint in time)
    // Ob fp32 lives in d_out until overwritten by final output.
    // Wc: bf16 weight copies (1.38 MB), total 181.2 MB (<= 192.7 MB proven).
    const size_t NXf = (size_t)BB * DIMC * PP;        // 12,845,056 floats
    float* X1    = (float*)d_ws;
    char*  Bbase = (char*)d_ws + NXf * 4;
    bf16*  Hb    = (bf16*)Bbase;
    float* Qb    = (float*)Bbase;                     // aliases Hb, disjoint in time
    char*  Cbase = Bbase + (size_t)BB * HIDC * PP * 2;
    float* QKV   = (float*)Cbase;
    float* X2    = (float*)Cbase;                     // aliases QKV, disjoint in time
    bf16*  Wc    = (bf16*)(Cbase + (size_t)BB * 384 * PP * 4);
    float* Ob    = (float*)d_out;
    float* outp  = (float*)d_out;

    bf16* Wf0w1 = Wc;                  // [512][256]
    bf16* Wf0w2 = Wf0w1 + 131072;      // [256][512]
    bf16* Wf1w1 = Wf0w2 + 131072;      // [512][256]
    bf16* Wf1w2 = Wf1w1 + 131072;      // [256][512]
    bf16* Wqkv  = Wf1w2 + 131072;      // [384][256]
    bf16* Wproj = Wqkv + 98304;        // [256][256]

    dim3 blk(256);

    // 0) weights fp32 -> bf16
    cvt_f2b<<<512, blk, 0, stream>>>(f0w1, Wf0w1, 131072);
    cvt_f2b<<<512, blk, 0, stream>>>(f0w2, Wf0w2, 131072);
    cvt_f2b<<<512, blk, 0, stream>>>(f1w1, Wf1w1, 131072);
    cvt_f2b<<<512, blk, 0, stream>>>(f1w2, Wf1w2, 131072);
    cvt_f2b<<<384, blk, 0, stream>>>(qkv_w, Wqkv, 98304);
    cvt_f2b<<<256, blk, 0, stream>>>(proj_w, Wproj, 65536);

    // 1) x = x + dw0(x)
    dw3x3_kernel<<<BB * DIMC, blk, 0, stream>>>(x0, dw0_w, dw0_s, dw0_b, X1);

    // 2-3) ffn0
    gemm_mfma<float, bf16, true, false><<<dim3(13, HIDC / 64, BB), blk, 0, stream>>>(
        Wf0w1, X1, f0s1, f0b1, nullptr, Hb, HIDC, DIMC);
    gemm_mfma<bf16, float, false, true><<<dim3(13, DIMC / 64, BB), blk, 0, stream>>>(
        Wf0w2, Hb, f0s2, f0b2, X1, X1, DIMC, HIDC);

    // 4-7) attention
    gemm_mfma<float, float, false, false><<<dim3(13, 384 / 64, BB), blk, 0, stream>>>(
        Wqkv, X1, qkv_s, qkv_b, nullptr, QKV, 384, DIMC);
    dws5x5_kernel<<<BB * 64, blk, 0, stream>>>(QKV, dws_w, dws_s, dws_b, Qb);
    attn_kernel<<<BB * NHH * 16, blk, 0, stream>>>(Qb, QKV, pos, Ob);
    gemm_mfma<float, float, false, true><<<dim3(13, DIMC / 64, BB), blk, 0, stream>>>(
        Wproj, Ob, proj_s, proj_b, X1, X1, DIMC, DIMC);

    // 8) x = x + dw1(x)   (QKV dead -> X2)
    dw3x3_kernel<<<BB * DIMC, blk, 0, stream>>>(X1, dw1_w, dw1_s, dw1_b, X2);

    // 9-10) ffn1, final fp32 NCHW to d_out
    gemm_mfma<float, bf16, true, false><<<dim3(13, HIDC / 64, BB), blk, 0, stream>>>(
        Wf1w1, X2, f1s1, f1b1, nullptr, Hb, HIDC, DIMC);
    gemm_mfma<bf16, float, false, true><<<dim3(13, DIMC / 64, BB), blk, 0, stream>>>(
        Wf1w2, Hb, f1s2, f1b2, X2, outp, DIMC, HIDC);
}